// Round 7
// baseline (770.799 us; speedup 1.0000x reference)
//
#include <hip/hip_runtime.h>
#include <hip/hip_bf16.h>
#include <math.h>

#define T_LEN 32768
#define NB 4
#define NC 64
#define NL 18
#define TILE_T 64

typedef __attribute__((ext_vector_type(8))) short s16x8;
typedef __attribute__((ext_vector_type(4))) float f32x4;
#define MFMA_BF16 __builtin_amdgcn_mfma_f32_16x16x32_bf16

__device__ inline unsigned short f2bf(float f) {
    unsigned u = __builtin_bit_cast(unsigned, f);
    unsigned r = u + 0x7FFFu + ((u >> 16) & 1u);
    return (unsigned short)(r >> 16);
}
__device__ inline unsigned pack_bf2(float a, float b) {
    return (unsigned)f2bf(a) | ((unsigned)f2bf(b) << 16);
}
__device__ inline float fast_sigmoid(float x) {
    return __builtin_amdgcn_rcpf(1.f + __expf(-x));
}
__device__ inline float fast_tanh(float x) {
    return 1.f - 2.f * __builtin_amdgcn_rcpf(1.f + __expf(2.f * x));
}

// ------------------------------------------------------------------
// prep: weights only (input conv fused into layer 0):
//   Wh bf16 [L][128co][192K] (K=k*64+ci); Wr bf16 [L][64co][64ci];
//   out init = mix_b; zerobuf = 0
// ------------------------------------------------------------------
__global__ void prep_kernel(const float* __restrict__ hid_w,
                            const float* __restrict__ res_w,
                            const float* __restrict__ mix_b,
                            unsigned short* __restrict__ Wh,
                            unsigned short* __restrict__ Wr,
                            float* __restrict__ out,
                            float* __restrict__ zerobuf) {
    const int nW1 = NL * 128 * 192;        // 442368
    const int nW2 = NL * 64 * 64;          // 73728
    const int nOut = NB * T_LEN;           // 131072
    const int total = nW1 + nW2 + nOut + 32;
    for (int gid = blockIdx.x * blockDim.x + threadIdx.x; gid < total;
         gid += gridDim.x * blockDim.x) {
        if (gid < nW1) {
            int K = gid % 192;
            int co = (gid / 192) & 127;
            int i = gid / (192 * 128);
            int kt = K >> 6, ci = K & 63;
            Wh[gid] = f2bf(hid_w[((i * 128 + co) * 64 + ci) * 3 + kt]);
        } else if (gid < nW1 + nW2) {
            int q = gid - nW1;
            int c = q & 63, co = (q >> 6) & 63, i = q >> 12;
            Wr[q] = f2bf(res_w[(i * 64 + co) * 64 + c]);
        } else if (gid < nW1 + nW2 + nOut) {
            out[gid - (nW1 + nW2)] = mix_b[0];
        } else {
            zerobuf[gid - (nW1 + nW2 + nOut)] = 0.f;
        }
    }
}

// ------------------------------------------------------------------
// fused layer. 256 thr = 4 waves; tile = (b, 64 t). Templated on DIL.
// FIRST: stage X by computing input conv from x directly (t<0 -> ZERO,
//        matching the reference's zero-padded conv input).
// LAST:  skip-only (no res GEMM, no activation writes).
// ------------------------------------------------------------------
template <int DIL, bool FIRST, bool LAST>
__launch_bounds__(256, 5)
__global__ void layer_kernel(const float* __restrict__ actF,       // fp32 in
                             const unsigned short* __restrict__ actS, // bf16 in
                             float* __restrict__ outF,              // fp32 out
                             unsigned short* __restrict__ outS,     // bf16 out
                             const unsigned short* __restrict__ Wh, // [128][192]
                             const float* __restrict__ hb,          // [128]
                             const unsigned short* __restrict__ Wr, // [64][64]
                             const float* __restrict__ rb,          // [64]
                             const float* __restrict__ mw,          // [64]
                             float* __restrict__ skip,              // [B][T]
                             const float* __restrict__ zerobuf,
                             const float* __restrict__ x,           // [B][T]
                             const float* __restrict__ in_w,        // [64]
                             const float* __restrict__ in_b) {      // [64]
    constexpr bool UNI = (DIL < 64);
    constexpr int R = UNI ? (64 + 2 * DIL) : 192;   // staged rows
    constexpr int SLOTS = R * 8;                     // 16B chunks
    constexpr int JMAX = (SLOTS + 255) / 256;        // lds-load instrs/wave

    __shared__ uint4 Xs[1536];   // staged X rows (swizzled); later out-stage
    __shared__ uint4 Gs[512];    // gated [64t][64c] bf16, swizzled

    const int tid = threadIdx.x;
    const int w = tid >> 6;
    const int l = tid & 63;
    const int lo = l & 15;
    const int hi = l >> 4;
    const int b = blockIdx.y;
    const int tile = (blockIdx.x & 7) * 64 + (blockIdx.x >> 3);  // XCD swizzle
    const int t0 = tile * TILE_T;
    const int m0 = 16 * w;
    const int c0 = m0 + 4 * hi;

    const float* actB = actF + (size_t)b * T_LEN * NC;
    const unsigned short* shad = actS + (size_t)b * T_LEN * NC;
    const float* xB = x + (size_t)b * T_LEN;

    // ---- stage X tile into LDS (swizzled [row][ci] bf16) ----
    if (FIRST) {
        // compute input conv on the fly: row r -> t = t0 + r - 2*DIL
        // t < 0 must stage ZERO (reference zero-pads the conv input)
#pragma unroll
        for (int j = 0; j < JMAX; j++) {
            int p = j * 256 + tid;
            if (p < SLOTS) {
                int row = p >> 3, ch = p & 7;
                int tg = t0 + row - 2 * DIL;
                unsigned uu[4] = {0u, 0u, 0u, 0u};
                if (tg >= 0) {
                    float a = xB[tg];
#pragma unroll
                    for (int e = 0; e < 4; e++) {
                        float v0 = a * in_w[ch * 8 + 2 * e] + in_b[ch * 8 + 2 * e];
                        float v1 = a * in_w[ch * 8 + 2 * e + 1] + in_b[ch * 8 + 2 * e + 1];
                        uu[e] = pack_bf2(v0, v1);
                    }
                }
                int byte = (row * 128 + ch * 16) ^ ((row & 7) << 4);
                *(uint4*)((char*)Xs + byte) = make_uint4(uu[0], uu[1], uu[2], uu[3]);
            }
        }
    } else {
        // async: bf16 shadow -> LDS, source pre-swizzled, dest linear
#pragma unroll
        for (int j = 0; j < JMAX; j++) {
            int s = (w * JMAX + j) * 64 + l;
            const void* src;
            if (s >= SLOTS) {
                src = (const void*)(zerobuf + (s & 7) * 4);
            } else {
                int row = s >> 3, ch = s & 7;
                int chunk = ch ^ (row & 7);
                int tg = t0 + (UNI ? (row - 2 * DIL)
                                   : (((row >> 6) - 2) * DIL + (row & 63)));
                src = (tg >= 0) ? (const void*)(shad + (size_t)tg * 64 + chunk * 8)
                                : (const void*)(zerobuf + chunk * 4);
            }
            __builtin_amdgcn_global_load_lds(
                (const __attribute__((address_space(1))) unsigned int*)src,
                (__attribute__((address_space(3))) unsigned int*)((char*)Xs +
                                                        (w * JMAX + j) * 1024),
                16, 0, 0);
        }
    }

    // ---- W fragments -> registers ----
    s16x8 AH[2][6];
    s16x8 AR[2];
#pragma unroll
    for (int mt = 0; mt < 2; mt++) {
        const unsigned short* wp = Wh + (size_t)(m0 + 64 * mt + lo) * 192;
#pragma unroll
        for (int s = 0; s < 6; s++)
            AH[mt][s] = *(const s16x8*)(wp + 32 * s + 8 * hi);
    }
    if (!LAST) {
#pragma unroll
        for (int s = 0; s < 2; s++)
            AR[s] = *(const s16x8*)(Wr + (size_t)(m0 + lo) * 64 + 32 * s + 8 * hi);
    }

    float bA[4], bB[4], rbv[4];
#pragma unroll
    for (int r = 0; r < 4; r++) {
        bA[r] = hb[c0 + r];
        bB[r] = hb[64 + c0 + r];
        rbv[r] = LAST ? 0.f : rb[c0 + r];
    }
    const float4 mw4 = *(const float4*)(mw + c0);

    // ---- residual input for epilogue (issue early, overlapped) ----
    float4 inp[4];
    if (!LAST) {
        if (FIRST) {
            const float4 iw4 = *(const float4*)(in_w + c0);
            const float4 ib4 = *(const float4*)(in_b + c0);
#pragma unroll
            for (int nt = 0; nt < 4; nt++) {
                float xv = xB[t0 + 16 * nt + lo];
                inp[nt] = make_float4(xv * iw4.x + ib4.x, xv * iw4.y + ib4.y,
                                      xv * iw4.z + ib4.z, xv * iw4.w + ib4.w);
            }
        } else {
#pragma unroll
            for (int nt = 0; nt < 4; nt++)
                inp[nt] =
                    *(const float4*)(actB + (size_t)(t0 + 16 * nt + lo) * 64 + c0);
        }
    }

    __syncthreads();   // staging (+vmcnt drain) complete

    // ---- hid GEMM: acc[mt][nt] over K=192 (3 taps x 64 ci) ----
    f32x4 acc[2][4];
#pragma unroll
    for (int mt = 0; mt < 2; mt++)
#pragma unroll
        for (int nt = 0; nt < 4; nt++)
            acc[mt][nt] = (f32x4){0.f, 0.f, 0.f, 0.f};

#pragma unroll
    for (int s = 0; s < 6; s++) {
        const int tap = s >> 1, half = s & 1;
#pragma unroll
        for (int nt = 0; nt < 4; nt++) {
            int t = 16 * nt + lo;
            int row = UNI ? (t + tap * DIL) : (tap * 64 + t);
            int byte = (row * 128 + half * 64 + hi * 16) ^ ((row & 7) << 4);
            s16x8 bx =
                __builtin_bit_cast(s16x8, ((const uint4*)Xs)[byte >> 4]);
            acc[0][nt] = MFMA_BF16(AH[0][s], bx, acc[0][nt], 0, 0, 0);
            acc[1][nt] = MFMA_BF16(AH[1][s], bx, acc[1][nt], 0, 0, 0);
        }
    }

    // ---- gating -> Gs + skip partial -> atomic ----
#pragma unroll
    for (int nt = 0; nt < 4; nt++) {
        float g[4];
#pragma unroll
        for (int r = 0; r < 4; r++) {
            float hA = acc[0][nt][r] + bA[r];
            float hB = acc[1][nt][r] + bB[r];
            g[r] = fast_tanh(hA) * fast_sigmoid(hB);
        }
        int t = 16 * nt + lo;
        if (!LAST) {
            int byte = (t * 128 + c0 * 2) ^ ((t & 7) << 4);
            ((uint2*)Gs)[byte >> 3] =
                make_uint2(pack_bf2(g[0], g[1]), pack_bf2(g[2], g[3]));
        }
        float sk = g[0] * mw4.x + g[1] * mw4.y + g[2] * mw4.z + g[3] * mw4.w;
        sk += __shfl_xor(sk, 16, 64);
        sk += __shfl_xor(sk, 32, 64);
        if (hi == 0)
            atomicAdd(skip + (size_t)b * T_LEN + t0 + t, sk);
    }
    if (LAST) return;

    __syncthreads();

    // ---- res GEMM over K=64 ----
    f32x4 acc2[4];
#pragma unroll
    for (int nt = 0; nt < 4; nt++) acc2[nt] = (f32x4){0.f, 0.f, 0.f, 0.f};
#pragma unroll
    for (int s = 0; s < 2; s++) {
#pragma unroll
        for (int nt = 0; nt < 4; nt++) {
            int t = 16 * nt + lo;
            int byte = (t * 128 + s * 64 + hi * 16) ^ ((t & 7) << 4);
            s16x8 bg =
                __builtin_bit_cast(s16x8, ((const uint4*)Gs)[byte >> 4]);
            acc2[nt] = MFMA_BF16(AR[s], bg, acc2[nt], 0, 0, 0);
        }
    }

    // ---- out-stage into LDS (Xs reused): fp32 [64t][64c] + bf16 shadow ----
    char* OutF = (char*)Xs;             // 16 KB
    char* OutB = (char*)Xs + 16384;     // 8 KB
#pragma unroll
    for (int nt = 0; nt < 4; nt++) {
        int t = 16 * nt + lo;
        float4 o;
        o.x = acc2[nt][0] + rbv[0] + inp[nt].x;
        o.y = acc2[nt][1] + rbv[1] + inp[nt].y;
        o.z = acc2[nt][2] + rbv[2] + inp[nt].z;
        o.w = acc2[nt][3] + rbv[3] + inp[nt].w;
        int chunkF = (4 * w + hi) ^ (t & 15);
        *(float4*)(OutF + t * 256 + chunkF * 16) = o;
        int byteB = (t * 128 + c0 * 2) ^ ((t & 7) << 4);
        *(uint2*)(OutB + byteB) =
            make_uint2(pack_bf2(o.x, o.y), pack_bf2(o.z, o.w));
    }
    __syncthreads();

    // ---- coalesced copy-out: full 128B lines ----
    float* gF = outF + (size_t)b * T_LEN * NC + (size_t)t0 * 64;
    unsigned short* gB = outS + (size_t)b * T_LEN * NC + (size_t)t0 * 64;
#pragma unroll
    for (int i = 0; i < 4; i++) {
        int u = i * 256 + tid;          // 1024 uint4 = 16 KB
        int t = u >> 4, ch = u & 15;
        uint4 v = *(const uint4*)(OutF + t * 256 + ((ch ^ (t & 15)) << 4));
        ((uint4*)gF)[u] = v;
    }
#pragma unroll
    for (int i = 0; i < 2; i++) {
        int u = i * 256 + tid;          // 512 uint4 = 8 KB
        int t = u >> 3, ch = u & 7;
        uint4 v = *(const uint4*)(OutB + t * 128 + ((ch ^ (t & 7)) << 4));
        ((uint4*)gB)[u] = v;
    }
}

// ------------------------------------------------------------------
extern "C" void kernel_launch(void* const* d_in, const int* in_sizes, int n_in,
                              void* d_out, int out_size, void* d_ws, size_t ws_size,
                              hipStream_t stream) {
    const float* x     = (const float*)d_in[0];
    const float* in_w  = (const float*)d_in[1];
    const float* in_b  = (const float*)d_in[2];
    const float* hid_w = (const float*)d_in[3];
    const float* hid_b = (const float*)d_in[4];
    const float* res_w = (const float*)d_in[5];
    const float* res_b = (const float*)d_in[6];
    const float* mix_w = (const float*)d_in[7];
    const float* mix_b = (const float*)d_in[8];
    float* out = (float*)d_out;

    const size_t actN = (size_t)NB * T_LEN * NC;  // 8388608
    float* A0 = (float*)d_ws;
    float* A1 = A0 + actN;
    unsigned short* S0 = (unsigned short*)(A1 + actN);
    unsigned short* S1 = S0 + actN;
    unsigned short* Wh = S1 + actN;
    unsigned short* Wr = Wh + (size_t)NL * 128 * 192;
    float* zerobuf = (float*)(Wr + (size_t)NL * 64 * 64);

    prep_kernel<<<512, 256, 0, stream>>>(hid_w, res_w, mix_b, Wh, Wr, out,
                                         zerobuf);

    static const int dils[NL] = {1, 2, 4, 8, 16, 32, 64, 128, 256,
                                 1, 2, 4, 8, 16, 32, 64, 128, 256};
    const float* srcF = A0;
    const unsigned short* srcS = S0;
    float* dstF = A1;
    unsigned short* dstS = S1;
    dim3 grid(T_LEN / TILE_T, NB);

#define LL(D, F, L)                                                           \
    layer_kernel<D, F, L><<<grid, 256, 0, stream>>>(                          \
        srcF, srcS, dstF, dstS, Wh + (size_t)i * 128 * 192,                   \
        hid_b + (size_t)i * 128, Wr + (size_t)i * 64 * 64,                    \
        res_b + (size_t)i * 64, mix_w + (size_t)i * 64, out, zerobuf, x,      \
        in_w, in_b)

    for (int i = 0; i < NL; i++) {
        if (i == 0) {
            LL(1, true, false);
        } else if (i == NL - 1) {
            LL(256, false, true);
        } else {
            switch (dils[i]) {
                case 1:   LL(1, false, false);   break;
                case 2:   LL(2, false, false);   break;
                case 4:   LL(4, false, false);   break;
                case 8:   LL(8, false, false);   break;
                case 16:  LL(16, false, false);  break;
                case 32:  LL(32, false, false);  break;
                case 64:  LL(64, false, false);  break;
                case 128: LL(128, false, false); break;
                case 256: LL(256, false, false); break;
            }
        }
        const float* tF = srcF; srcF = dstF; dstF = (float*)tF;
        const unsigned short* tS = srcS; srcS = dstS; dstS = (unsigned short*)tS;
    }
#undef LL
}

// Round 8
// 499.264 us; speedup vs baseline: 1.5439x; 1.5439x over previous
//
#include <hip/hip_runtime.h>
#include <hip/hip_bf16.h>
#include <math.h>

#define T_LEN 32768
#define NB 4
#define NC 64
#define NL 18
#define TILE_T 64

typedef __attribute__((ext_vector_type(8))) short s16x8;
typedef __attribute__((ext_vector_type(4))) float f32x4;
#define MFMA_BF16 __builtin_amdgcn_mfma_f32_16x16x32_bf16

__device__ inline unsigned short f2bf(float f) {
    unsigned u = __builtin_bit_cast(unsigned, f);
    unsigned r = u + 0x7FFFu + ((u >> 16) & 1u);
    return (unsigned short)(r >> 16);
}
__device__ inline unsigned pack_bf2(float a, float b) {
    return (unsigned)f2bf(a) | ((unsigned)f2bf(b) << 16);
}
__device__ inline float fast_sigmoid(float x) {
    return __builtin_amdgcn_rcpf(1.f + __expf(-x));
}
__device__ inline float fast_tanh(float x) {
    return 1.f - 2.f * __builtin_amdgcn_rcpf(1.f + __expf(2.f * x));
}

// ------------------------------------------------------------------
// prep: weights only (input conv fused into layer 0):
//   Wh bf16 [L][128co][192K] (K=k*64+ci); Wr bf16 [L][64co][64ci];
//   out init = mix_b; zerobuf = 0
// ------------------------------------------------------------------
__global__ void prep_kernel(const float* __restrict__ hid_w,
                            const float* __restrict__ res_w,
                            const float* __restrict__ mix_b,
                            unsigned short* __restrict__ Wh,
                            unsigned short* __restrict__ Wr,
                            float* __restrict__ out,
                            float* __restrict__ zerobuf) {
    const int nW1 = NL * 128 * 192;        // 442368
    const int nW2 = NL * 64 * 64;          // 73728
    const int nOut = NB * T_LEN;           // 131072
    const int total = nW1 + nW2 + nOut + 32;
    for (int gid = blockIdx.x * blockDim.x + threadIdx.x; gid < total;
         gid += gridDim.x * blockDim.x) {
        if (gid < nW1) {
            int K = gid % 192;
            int co = (gid / 192) & 127;
            int i = gid / (192 * 128);
            int kt = K >> 6, ci = K & 63;
            Wh[gid] = f2bf(hid_w[((i * 128 + co) * 64 + ci) * 3 + kt]);
        } else if (gid < nW1 + nW2) {
            int q = gid - nW1;
            int c = q & 63, co = (q >> 6) & 63, i = q >> 12;
            Wr[q] = f2bf(res_w[(i * 64 + co) * 64 + c]);
        } else if (gid < nW1 + nW2 + nOut) {
            out[gid - (nW1 + nW2)] = mix_b[0];
        } else {
            zerobuf[gid - (nW1 + nW2 + nOut)] = 0.f;
        }
    }
}

// ------------------------------------------------------------------
// fused layer. 256 thr = 4 waves; tile = (b, 64 t). Templated on DIL.
// FIRST: stage X by computing input conv from x directly (t<0 -> ZERO).
// LAST:  skip-only (no res GEMM, no activation writes).
// skip: per-wave shfl reduce -> Sk LDS -> one plain += per t (NO atomics:
//       R7 showed 524K atomics/layer cost ~+120MB/layer HBM traffic).
// ------------------------------------------------------------------
template <int DIL, bool FIRST, bool LAST>
__launch_bounds__(256, 4)
__global__ void layer_kernel(const float* __restrict__ actF,       // fp32 in
                             const unsigned short* __restrict__ actS, // bf16 in
                             float* __restrict__ outF,              // fp32 out
                             unsigned short* __restrict__ outS,     // bf16 out
                             const unsigned short* __restrict__ Wh, // [128][192]
                             const float* __restrict__ hb,          // [128]
                             const unsigned short* __restrict__ Wr, // [64][64]
                             const float* __restrict__ rb,          // [64]
                             const float* __restrict__ mw,          // [64]
                             float* __restrict__ skip,              // [B][T]
                             const float* __restrict__ zerobuf,
                             const float* __restrict__ x,           // [B][T]
                             const float* __restrict__ in_w,        // [64]
                             const float* __restrict__ in_b) {      // [64]
    constexpr bool UNI = (DIL < 64);
    constexpr int R = UNI ? (64 + 2 * DIL) : 192;   // staged rows
    constexpr int SLOTS = R * 8;                     // 16B chunks
    constexpr int JMAX = (SLOTS + 255) / 256;        // lds-load instrs/wave

    __shared__ uint4 Xs[1536];   // staged X rows (swizzled); later out-stage
    __shared__ uint4 Gs[512];    // gated [64t][64c] bf16, swizzled
    __shared__ float Sk[256];    // skip partials [w][t]

    const int tid = threadIdx.x;
    const int w = tid >> 6;
    const int l = tid & 63;
    const int lo = l & 15;
    const int hi = l >> 4;
    const int b = blockIdx.y;
    const int tile = (blockIdx.x & 7) * 64 + (blockIdx.x >> 3);  // XCD swizzle
    const int t0 = tile * TILE_T;
    const int m0 = 16 * w;
    const int c0 = m0 + 4 * hi;

    const float* actB = actF + (size_t)b * T_LEN * NC;
    const unsigned short* shad = actS + (size_t)b * T_LEN * NC;
    const float* xB = x + (size_t)b * T_LEN;

    // ---- stage X tile into LDS (swizzled [row][ci] bf16) ----
    if (FIRST) {
        // compute input conv on the fly: row r -> t = t0 + r - 2*DIL
        // t < 0 stages ZERO (reference zero-pads the conv input)
#pragma unroll
        for (int j = 0; j < JMAX; j++) {
            int p = j * 256 + tid;
            if (p < SLOTS) {
                int row = p >> 3, ch = p & 7;
                int tg = t0 + row - 2 * DIL;
                unsigned uu[4] = {0u, 0u, 0u, 0u};
                if (tg >= 0) {
                    float a = xB[tg];
#pragma unroll
                    for (int e = 0; e < 4; e++) {
                        float v0 = a * in_w[ch * 8 + 2 * e] + in_b[ch * 8 + 2 * e];
                        float v1 = a * in_w[ch * 8 + 2 * e + 1] + in_b[ch * 8 + 2 * e + 1];
                        uu[e] = pack_bf2(v0, v1);
                    }
                }
                int byte = (row * 128 + ch * 16) ^ ((row & 7) << 4);
                *(uint4*)((char*)Xs + byte) = make_uint4(uu[0], uu[1], uu[2], uu[3]);
            }
        }
    } else {
        // async: bf16 shadow -> LDS, source pre-swizzled, dest linear
#pragma unroll
        for (int j = 0; j < JMAX; j++) {
            int s = (w * JMAX + j) * 64 + l;
            const void* src;
            if (s >= SLOTS) {
                src = (const void*)(zerobuf + (s & 7) * 4);
            } else {
                int row = s >> 3, ch = s & 7;
                int chunk = ch ^ (row & 7);
                int tg = t0 + (UNI ? (row - 2 * DIL)
                                   : (((row >> 6) - 2) * DIL + (row & 63)));
                src = (tg >= 0) ? (const void*)(shad + (size_t)tg * 64 + chunk * 8)
                                : (const void*)(zerobuf + chunk * 4);
            }
            __builtin_amdgcn_global_load_lds(
                (const __attribute__((address_space(1))) unsigned int*)src,
                (__attribute__((address_space(3))) unsigned int*)((char*)Xs +
                                                        (w * JMAX + j) * 1024),
                16, 0, 0);
        }
    }

    // ---- W fragments -> registers ----
    s16x8 AH[2][6];
    s16x8 AR[2];
#pragma unroll
    for (int mt = 0; mt < 2; mt++) {
        const unsigned short* wp = Wh + (size_t)(m0 + 64 * mt + lo) * 192;
#pragma unroll
        for (int s = 0; s < 6; s++)
            AH[mt][s] = *(const s16x8*)(wp + 32 * s + 8 * hi);
    }
    if (!LAST) {
#pragma unroll
        for (int s = 0; s < 2; s++)
            AR[s] = *(const s16x8*)(Wr + (size_t)(m0 + lo) * 64 + 32 * s + 8 * hi);
    }

    float bA[4], bB[4], rbv[4];
#pragma unroll
    for (int r = 0; r < 4; r++) {
        bA[r] = hb[c0 + r];
        bB[r] = hb[64 + c0 + r];
        rbv[r] = LAST ? 0.f : rb[c0 + r];
    }
    const float4 mw4 = *(const float4*)(mw + c0);

    // ---- residual input for epilogue (issue early, overlapped) ----
    float4 inp[4];
    if (!LAST) {
        if (FIRST) {
            const float4 iw4 = *(const float4*)(in_w + c0);
            const float4 ib4 = *(const float4*)(in_b + c0);
#pragma unroll
            for (int nt = 0; nt < 4; nt++) {
                float xv = xB[t0 + 16 * nt + lo];
                inp[nt] = make_float4(xv * iw4.x + ib4.x, xv * iw4.y + ib4.y,
                                      xv * iw4.z + ib4.z, xv * iw4.w + ib4.w);
            }
        } else {
#pragma unroll
            for (int nt = 0; nt < 4; nt++)
                inp[nt] =
                    *(const float4*)(actB + (size_t)(t0 + 16 * nt + lo) * 64 + c0);
        }
    }

    __syncthreads();   // staging (+vmcnt drain) complete

    // ---- hid GEMM: acc[mt][nt] over K=192 (3 taps x 64 ci) ----
    f32x4 acc[2][4];
#pragma unroll
    for (int mt = 0; mt < 2; mt++)
#pragma unroll
        for (int nt = 0; nt < 4; nt++)
            acc[mt][nt] = (f32x4){0.f, 0.f, 0.f, 0.f};

#pragma unroll
    for (int s = 0; s < 6; s++) {
        const int tap = s >> 1, half = s & 1;
#pragma unroll
        for (int nt = 0; nt < 4; nt++) {
            int t = 16 * nt + lo;
            int row = UNI ? (t + tap * DIL) : (tap * 64 + t);
            int byte = (row * 128 + half * 64 + hi * 16) ^ ((row & 7) << 4);
            s16x8 bx =
                __builtin_bit_cast(s16x8, ((const uint4*)Xs)[byte >> 4]);
            acc[0][nt] = MFMA_BF16(AH[0][s], bx, acc[0][nt], 0, 0, 0);
            acc[1][nt] = MFMA_BF16(AH[1][s], bx, acc[1][nt], 0, 0, 0);
        }
    }

    // ---- gating -> Gs + skip partials (shfl reduce -> Sk) ----
#pragma unroll
    for (int nt = 0; nt < 4; nt++) {
        float g[4];
#pragma unroll
        for (int r = 0; r < 4; r++) {
            float hA = acc[0][nt][r] + bA[r];
            float hB = acc[1][nt][r] + bB[r];
            g[r] = fast_tanh(hA) * fast_sigmoid(hB);
        }
        int t = 16 * nt + lo;
        if (!LAST) {
            int byte = (t * 128 + c0 * 2) ^ ((t & 7) << 4);
            ((uint2*)Gs)[byte >> 3] =
                make_uint2(pack_bf2(g[0], g[1]), pack_bf2(g[2], g[3]));
        }
        float sk = g[0] * mw4.x + g[1] * mw4.y + g[2] * mw4.z + g[3] * mw4.w;
        sk += __shfl_xor(sk, 16, 64);
        sk += __shfl_xor(sk, 32, 64);
        if (hi == 0) Sk[w * 64 + nt * 16 + lo] = sk;
    }
    __syncthreads();

    if (LAST) {
        if (tid < 64) {
            float s2 = Sk[tid] + Sk[64 + tid] + Sk[128 + tid] + Sk[192 + tid];
            skip[(size_t)b * T_LEN + t0 + tid] += s2;
        }
        return;
    }

    // ---- res GEMM over K=64 ----
    f32x4 acc2[4];
#pragma unroll
    for (int nt = 0; nt < 4; nt++) acc2[nt] = (f32x4){0.f, 0.f, 0.f, 0.f};
#pragma unroll
    for (int s = 0; s < 2; s++) {
#pragma unroll
        for (int nt = 0; nt < 4; nt++) {
            int t = 16 * nt + lo;
            int byte = (t * 128 + s * 64 + hi * 16) ^ ((t & 7) << 4);
            s16x8 bg =
                __builtin_bit_cast(s16x8, ((const uint4*)Gs)[byte >> 4]);
            acc2[nt] = MFMA_BF16(AR[s], bg, acc2[nt], 0, 0, 0);
        }
    }

    // ---- out-stage into LDS (Xs reused): fp32 [64t][64c] + bf16 shadow ----
    char* OutF = (char*)Xs;             // 16 KB
    char* OutB = (char*)Xs + 16384;     // 8 KB
#pragma unroll
    for (int nt = 0; nt < 4; nt++) {
        int t = 16 * nt + lo;
        float4 o;
        o.x = acc2[nt][0] + rbv[0] + inp[nt].x;
        o.y = acc2[nt][1] + rbv[1] + inp[nt].y;
        o.z = acc2[nt][2] + rbv[2] + inp[nt].z;
        o.w = acc2[nt][3] + rbv[3] + inp[nt].w;
        int chunkF = (4 * w + hi) ^ (t & 15);
        *(float4*)(OutF + t * 256 + chunkF * 16) = o;
        int byteB = (t * 128 + c0 * 2) ^ ((t & 7) << 4);
        *(uint2*)(OutB + byteB) =
            make_uint2(pack_bf2(o.x, o.y), pack_bf2(o.z, o.w));
    }

    // ---- skip: one plain += per t (Sk is a separate buffer, no clobber) ----
    if (tid < 64) {
        float s2 = Sk[tid] + Sk[64 + tid] + Sk[128 + tid] + Sk[192 + tid];
        skip[(size_t)b * T_LEN + t0 + tid] += s2;
    }
    __syncthreads();

    // ---- coalesced copy-out: full 128B lines ----
    float* gF = outF + (size_t)b * T_LEN * NC + (size_t)t0 * 64;
    unsigned short* gB = outS + (size_t)b * T_LEN * NC + (size_t)t0 * 64;
#pragma unroll
    for (int i = 0; i < 4; i++) {
        int u = i * 256 + tid;          // 1024 uint4 = 16 KB
        int t = u >> 4, ch = u & 15;
        uint4 v = *(const uint4*)(OutF + t * 256 + ((ch ^ (t & 15)) << 4));
        ((uint4*)gF)[u] = v;
    }
#pragma unroll
    for (int i = 0; i < 2; i++) {
        int u = i * 256 + tid;          // 512 uint4 = 8 KB
        int t = u >> 3, ch = u & 7;
        uint4 v = *(const uint4*)(OutB + t * 128 + ((ch ^ (t & 7)) << 4));
        ((uint4*)gB)[u] = v;
    }
}

// ------------------------------------------------------------------
extern "C" void kernel_launch(void* const* d_in, const int* in_sizes, int n_in,
                              void* d_out, int out_size, void* d_ws, size_t ws_size,
                              hipStream_t stream) {
    const float* x     = (const float*)d_in[0];
    const float* in_w  = (const float*)d_in[1];
    const float* in_b  = (const float*)d_in[2];
    const float* hid_w = (const float*)d_in[3];
    const float* hid_b = (const float*)d_in[4];
    const float* res_w = (const float*)d_in[5];
    const float* res_b = (const float*)d_in[6];
    const float* mix_w = (const float*)d_in[7];
    const float* mix_b = (const float*)d_in[8];
    float* out = (float*)d_out;

    const size_t actN = (size_t)NB * T_LEN * NC;  // 8388608
    float* A0 = (float*)d_ws;
    float* A1 = A0 + actN;
    unsigned short* S0 = (unsigned short*)(A1 + actN);
    unsigned short* S1 = S0 + actN;
    unsigned short* Wh = S1 + actN;
    unsigned short* Wr = Wh + (size_t)NL * 128 * 192;
    float* zerobuf = (float*)(Wr + (size_t)NL * 64 * 64);

    prep_kernel<<<512, 256, 0, stream>>>(hid_w, res_w, mix_b, Wh, Wr, out,
                                         zerobuf);

    static const int dils[NL] = {1, 2, 4, 8, 16, 32, 64, 128, 256,
                                 1, 2, 4, 8, 16, 32, 64, 128, 256};
    const float* srcF = A0;
    const unsigned short* srcS = S0;
    float* dstF = A1;
    unsigned short* dstS = S1;
    dim3 grid(T_LEN / TILE_T, NB);

#define LL(D, F, L)                                                           \
    layer_kernel<D, F, L><<<grid, 256, 0, stream>>>(                          \
        srcF, srcS, dstF, dstS, Wh + (size_t)i * 128 * 192,                   \
        hid_b + (size_t)i * 128, Wr + (size_t)i * 64 * 64,                    \
        res_b + (size_t)i * 64, mix_w + (size_t)i * 64, out, zerobuf, x,      \
        in_w, in_b)

    for (int i = 0; i < NL; i++) {
        if (i == 0) {
            LL(1, true, false);
        } else if (i == NL - 1) {
            LL(256, false, true);
        } else {
            switch (dils[i]) {
                case 1:   LL(1, false, false);   break;
                case 2:   LL(2, false, false);   break;
                case 4:   LL(4, false, false);   break;
                case 8:   LL(8, false, false);   break;
                case 16:  LL(16, false, false);  break;
                case 32:  LL(32, false, false);  break;
                case 64:  LL(64, false, false);  break;
                case 128: LL(128, false, false); break;
                case 256: LL(256, false, false); break;
            }
        }
        const float* tF = srcF; srcF = dstF; dstF = (float*)tF;
        const unsigned short* tS = srcS; srcS = dstS; dstS = (unsigned short*)tS;
    }
#undef LL
}

// Round 9
// 382.200 us; speedup vs baseline: 2.0167x; 1.3063x over previous
//
#include <hip/hip_runtime.h>
#include <math.h>

#define T_LEN 32768
#define NB 4
#define NC 64
#define NL 18
#define TILE_T 64

typedef __attribute__((ext_vector_type(8))) short s16x8;
typedef __attribute__((ext_vector_type(4))) float f32x4;
#define MFMA_F16 __builtin_amdgcn_mfma_f32_16x16x32_f16

__device__ inline unsigned short f2h(float f) {
    _Float16 h = (_Float16)f;       // RNE
    return __builtin_bit_cast(unsigned short, h);
}
__device__ inline unsigned pack_h2(float a, float b) {
    return (unsigned)f2h(a) | ((unsigned)f2h(b) << 16);
}
__device__ inline float h2f(unsigned short u) {
    return (float)__builtin_bit_cast(_Float16, u);
}
__device__ inline float fast_sigmoid(float x) {
    return __builtin_amdgcn_rcpf(1.f + __expf(-x));
}
__device__ inline float fast_tanh(float x) {
    return 1.f - 2.f * __builtin_amdgcn_rcpf(1.f + __expf(2.f * x));
}

// ------------------------------------------------------------------
// prep: weights -> fp16:
//   Wh [L][128co][192K] (K=k*64+ci); Wr [L][64co][64ci];
//   out init = mix_b; zerobuf = 0
// ------------------------------------------------------------------
__global__ void prep_kernel(const float* __restrict__ hid_w,
                            const float* __restrict__ res_w,
                            const float* __restrict__ mix_b,
                            unsigned short* __restrict__ Wh,
                            unsigned short* __restrict__ Wr,
                            float* __restrict__ out,
                            float* __restrict__ zerobuf) {
    const int nW1 = NL * 128 * 192;        // 442368
    const int nW2 = NL * 64 * 64;          // 73728
    const int nOut = NB * T_LEN;           // 131072
    const int total = nW1 + nW2 + nOut + 32;
    for (int gid = blockIdx.x * blockDim.x + threadIdx.x; gid < total;
         gid += gridDim.x * blockDim.x) {
        if (gid < nW1) {
            int K = gid % 192;
            int co = (gid / 192) & 127;
            int i = gid / (192 * 128);
            int kt = K >> 6, ci = K & 63;
            Wh[gid] = f2h(hid_w[((i * 128 + co) * 64 + ci) * 3 + kt]);
        } else if (gid < nW1 + nW2) {
            int q = gid - nW1;
            int c = q & 63, co = (q >> 6) & 63, i = q >> 12;
            Wr[q] = f2h(res_w[(i * 64 + co) * 64 + c]);
        } else if (gid < nW1 + nW2 + nOut) {
            out[gid - (nW1 + nW2)] = mix_b[0];
        } else {
            zerobuf[gid - (nW1 + nW2 + nOut)] = 0.f;
        }
    }
}

// ------------------------------------------------------------------
// fused layer, single fp16 activation stream. 256 thr = 4 waves;
// tile = (b, 64 t). Residual input comes from the LDS-staged tap-2 rows
// (no separate global read). Templated on DIL.
// ------------------------------------------------------------------
template <int DIL, bool FIRST, bool LAST>
__launch_bounds__(256, 4)
__global__ void layer_kernel(const unsigned short* __restrict__ actH, // fp16 in
                             unsigned short* __restrict__ outH,       // fp16 out
                             const unsigned short* __restrict__ Wh, // [128][192]
                             const float* __restrict__ hb,          // [128]
                             const unsigned short* __restrict__ Wr, // [64][64]
                             const float* __restrict__ rb,          // [64]
                             const float* __restrict__ mw,          // [64]
                             float* __restrict__ skip,              // [B][T]
                             const float* __restrict__ zerobuf,
                             const float* __restrict__ x,           // [B][T]
                             const float* __restrict__ in_w,        // [64]
                             const float* __restrict__ in_b) {      // [64]
    constexpr bool UNI = (DIL < 64);
    constexpr int R = UNI ? (64 + 2 * DIL) : 192;   // staged rows
    constexpr int SLOTS = R * 8;                     // 16B chunks
    constexpr int JMAX = (SLOTS + 255) / 256;        // lds-load instrs/wave

    __shared__ uint4 Xs[1536];   // staged X rows (swizzled); later out-stage
    __shared__ uint4 Gs[512];    // gated [64t][64c] fp16, swizzled
    __shared__ float Sk[256];    // skip partials [w][t]

    const int tid = threadIdx.x;
    const int w = tid >> 6;
    const int l = tid & 63;
    const int lo = l & 15;
    const int hi = l >> 4;
    const int b = blockIdx.y;
    const int tile = (blockIdx.x & 7) * 64 + (blockIdx.x >> 3);  // XCD swizzle
    const int t0 = tile * TILE_T;
    const int m0 = 16 * w;
    const int c0 = m0 + 4 * hi;

    const unsigned short* actB = actH + (size_t)b * T_LEN * NC;
    const float* xB = x + (size_t)b * T_LEN;

    // ---- stage X tile into LDS (swizzled [row][ci] fp16, 128B rows) ----
    if (FIRST) {
        // input conv on the fly: row r -> t = t0 + r - 2*DIL; t<0 -> ZERO
#pragma unroll
        for (int j = 0; j < JMAX; j++) {
            int p = j * 256 + tid;
            if (p < SLOTS) {
                int row = p >> 3, ch = p & 7;
                int tg = t0 + row - 2 * DIL;
                unsigned uu[4] = {0u, 0u, 0u, 0u};
                if (tg >= 0) {
                    float a = xB[tg];
#pragma unroll
                    for (int e = 0; e < 4; e++) {
                        float v0 = a * in_w[ch * 8 + 2 * e] + in_b[ch * 8 + 2 * e];
                        float v1 = a * in_w[ch * 8 + 2 * e + 1] + in_b[ch * 8 + 2 * e + 1];
                        uu[e] = pack_h2(v0, v1);
                    }
                }
                int byte = (row * 128 + ch * 16) ^ ((row & 7) << 4);
                *(uint4*)((char*)Xs + byte) = make_uint4(uu[0], uu[1], uu[2], uu[3]);
            }
        }
    } else {
        // async: fp16 stream -> LDS, source pre-swizzled, dest linear
#pragma unroll
        for (int j = 0; j < JMAX; j++) {
            int s = (w * JMAX + j) * 64 + l;
            const void* src;
            if (s >= SLOTS) {
                src = (const void*)(zerobuf + (s & 7) * 4);
            } else {
                int row = s >> 3, ch = s & 7;
                int chunk = ch ^ (row & 7);
                int tg = t0 + (UNI ? (row - 2 * DIL)
                                   : (((row >> 6) - 2) * DIL + (row & 63)));
                src = (tg >= 0) ? (const void*)(actB + (size_t)tg * 64 + chunk * 8)
                                : (const void*)(zerobuf + chunk * 4);
            }
            __builtin_amdgcn_global_load_lds(
                (const __attribute__((address_space(1))) unsigned int*)src,
                (__attribute__((address_space(3))) unsigned int*)((char*)Xs +
                                                        (w * JMAX + j) * 1024),
                16, 0, 0);
        }
    }

    // ---- W fragments -> registers ----
    s16x8 AH[2][6];
    s16x8 AR[2];
#pragma unroll
    for (int mt = 0; mt < 2; mt++) {
        const unsigned short* wp = Wh + (size_t)(m0 + 64 * mt + lo) * 192;
#pragma unroll
        for (int s = 0; s < 6; s++)
            AH[mt][s] = *(const s16x8*)(wp + 32 * s + 8 * hi);
    }
    if (!LAST) {
#pragma unroll
        for (int s = 0; s < 2; s++)
            AR[s] = *(const s16x8*)(Wr + (size_t)(m0 + lo) * 64 + 32 * s + 8 * hi);
    }

    float bA[4], bB[4], rbv[4];
#pragma unroll
    for (int r = 0; r < 4; r++) {
        bA[r] = hb[c0 + r];
        bB[r] = hb[64 + c0 + r];
        rbv[r] = LAST ? 0.f : rb[c0 + r];
    }
    const float4 mw4 = *(const float4*)(mw + c0);

    __syncthreads();   // staging (+vmcnt drain) complete

    // ---- hid GEMM: acc[mt][nt] over K=192 (3 taps x 64 ci) ----
    f32x4 acc[2][4];
#pragma unroll
    for (int mt = 0; mt < 2; mt++)
#pragma unroll
        for (int nt = 0; nt < 4; nt++)
            acc[mt][nt] = (f32x4){0.f, 0.f, 0.f, 0.f};

#pragma unroll
    for (int s = 0; s < 6; s++) {
        const int tap = s >> 1, half = s & 1;
#pragma unroll
        for (int nt = 0; nt < 4; nt++) {
            int t = 16 * nt + lo;
            int row = UNI ? (t + tap * DIL) : (tap * 64 + t);
            int byte = (row * 128 + half * 64 + hi * 16) ^ ((row & 7) << 4);
            s16x8 bx =
                __builtin_bit_cast(s16x8, ((const uint4*)Xs)[byte >> 4]);
            acc[0][nt] = MFMA_F16(AH[0][s], bx, acc[0][nt], 0, 0, 0);
            acc[1][nt] = MFMA_F16(AH[1][s], bx, acc[1][nt], 0, 0, 0);
        }
    }

    // ---- residual input from LDS tap-2 rows (tile itself) ----
    float4 inp[4];
    if (!LAST) {
#pragma unroll
        for (int nt = 0; nt < 4; nt++) {
            int t = 16 * nt + lo;
            int rowI = UNI ? (t + 2 * DIL) : (128 + t);
            int byteI = (rowI * 128 + c0 * 2) ^ ((rowI & 7) << 4);
            uint2 hv = *(const uint2*)((char*)Xs + byteI);
            inp[nt] = make_float4(h2f((unsigned short)(hv.x & 0xffff)),
                                  h2f((unsigned short)(hv.x >> 16)),
                                  h2f((unsigned short)(hv.y & 0xffff)),
                                  h2f((unsigned short)(hv.y >> 16)));
        }
    }

    // ---- gating -> Gs + skip partials (shfl reduce -> Sk) ----
#pragma unroll
    for (int nt = 0; nt < 4; nt++) {
        float g[4];
#pragma unroll
        for (int r = 0; r < 4; r++) {
            float hA = acc[0][nt][r] + bA[r];
            float hB = acc[1][nt][r] + bB[r];
            g[r] = fast_tanh(hA) * fast_sigmoid(hB);
        }
        int t = 16 * nt + lo;
        if (!LAST) {
            int byte = (t * 128 + c0 * 2) ^ ((t & 7) << 4);
            ((uint2*)Gs)[byte >> 3] =
                make_uint2(pack_h2(g[0], g[1]), pack_h2(g[2], g[3]));
        }
        float sk = g[0] * mw4.x + g[1] * mw4.y + g[2] * mw4.z + g[3] * mw4.w;
        sk += __shfl_xor(sk, 16, 64);
        sk += __shfl_xor(sk, 32, 64);
        if (hi == 0) Sk[w * 64 + nt * 16 + lo] = sk;
    }
    __syncthreads();

    if (LAST) {
        if (tid < 64) {
            float s2 = Sk[tid] + Sk[64 + tid] + Sk[128 + tid] + Sk[192 + tid];
            skip[(size_t)b * T_LEN + t0 + tid] += s2;
        }
        return;
    }

    // ---- res GEMM over K=64 ----
    f32x4 acc2[4];
#pragma unroll
    for (int nt = 0; nt < 4; nt++) acc2[nt] = (f32x4){0.f, 0.f, 0.f, 0.f};
#pragma unroll
    for (int s = 0; s < 2; s++) {
#pragma unroll
        for (int nt = 0; nt < 4; nt++) {
            int t = 16 * nt + lo;
            int byte = (t * 128 + s * 64 + hi * 16) ^ ((t & 7) << 4);
            s16x8 bg =
                __builtin_bit_cast(s16x8, ((const uint4*)Gs)[byte >> 4]);
            acc2[nt] = MFMA_F16(AR[s], bg, acc2[nt], 0, 0, 0);
        }
    }

    // ---- out-stage into LDS (Xs reused): fp16 [64t][64c], swizzled ----
    char* OutH = (char*)Xs;             // 8 KB
#pragma unroll
    for (int nt = 0; nt < 4; nt++) {
        int t = 16 * nt + lo;
        float ox = acc2[nt][0] + rbv[0] + inp[nt].x;
        float oy = acc2[nt][1] + rbv[1] + inp[nt].y;
        float oz = acc2[nt][2] + rbv[2] + inp[nt].z;
        float ow = acc2[nt][3] + rbv[3] + inp[nt].w;
        int byteB = (t * 128 + c0 * 2) ^ ((t & 7) << 4);
        *(uint2*)(OutH + byteB) = make_uint2(pack_h2(ox, oy), pack_h2(oz, ow));
    }

    // ---- skip: one plain += per t ----
    if (tid < 64) {
        float s2 = Sk[tid] + Sk[64 + tid] + Sk[128 + tid] + Sk[192 + tid];
        skip[(size_t)b * T_LEN + t0 + tid] += s2;
    }
    __syncthreads();

    // ---- coalesced copy-out: full 128B lines ----
    unsigned short* gH = outH + (size_t)b * T_LEN * NC + (size_t)t0 * 64;
#pragma unroll
    for (int i = 0; i < 2; i++) {
        int u = i * 256 + tid;          // 512 uint4 = 8 KB
        int t = u >> 3, ch = u & 7;
        uint4 v = *(const uint4*)(OutH + t * 128 + ((ch ^ (t & 7)) << 4));
        ((uint4*)gH)[u] = v;
    }
}

// ------------------------------------------------------------------
extern "C" void kernel_launch(void* const* d_in, const int* in_sizes, int n_in,
                              void* d_out, int out_size, void* d_ws, size_t ws_size,
                              hipStream_t stream) {
    const float* x     = (const float*)d_in[0];
    const float* in_w  = (const float*)d_in[1];
    const float* in_b  = (const float*)d_in[2];
    const float* hid_w = (const float*)d_in[3];
    const float* hid_b = (const float*)d_in[4];
    const float* res_w = (const float*)d_in[5];
    const float* res_b = (const float*)d_in[6];
    const float* mix_w = (const float*)d_in[7];
    const float* mix_b = (const float*)d_in[8];
    float* out = (float*)d_out;

    const size_t actN = (size_t)NB * T_LEN * NC;  // 8388608
    unsigned short* H0 = (unsigned short*)d_ws;
    unsigned short* H1 = H0 + actN;
    unsigned short* Wh = H1 + actN;
    unsigned short* Wr = Wh + (size_t)NL * 128 * 192;
    float* zerobuf = (float*)(Wr + (size_t)NL * 64 * 64);

    prep_kernel<<<512, 256, 0, stream>>>(hid_w, res_w, mix_b, Wh, Wr, out,
                                         zerobuf);

    static const int dils[NL] = {1, 2, 4, 8, 16, 32, 64, 128, 256,
                                 1, 2, 4, 8, 16, 32, 64, 128, 256};
    const unsigned short* srcH = H0;
    unsigned short* dstH = H1;
    dim3 grid(T_LEN / TILE_T, NB);

#define LL(D, F, L)                                                           \
    layer_kernel<D, F, L><<<grid, 256, 0, stream>>>(                          \
        srcH, dstH, Wh + (size_t)i * 128 * 192, hid_b + (size_t)i * 128,      \
        Wr + (size_t)i * 64 * 64, res_b + (size_t)i * 64,                     \
        mix_w + (size_t)i * 64, out, zerobuf, x, in_w, in_b)

    for (int i = 0; i < NL; i++) {
        if (i == 0) {
            LL(1, true, false);
        } else if (i == NL - 1) {
            LL(256, false, true);
        } else {
            switch (dils[i]) {
                case 1:   LL(1, false, false);   break;
                case 2:   LL(2, false, false);   break;
                case 4:   LL(4, false, false);   break;
                case 8:   LL(8, false, false);   break;
                case 16:  LL(16, false, false);  break;
                case 32:  LL(32, false, false);  break;
                case 64:  LL(64, false, false);  break;
                case 128: LL(128, false, false); break;
                case 256: LL(256, false, false); break;
            }
        }
        const unsigned short* tH = srcH; srcH = dstH; dstH = (unsigned short*)tH;
    }
#undef LL
}